// Round 19
// baseline (139.758 us; speedup 1.0000x reference)
//
#include <hip/hip_runtime.h>
#include <math.h>

#define BB 2
#define SS 2048
#define EE 1024
#define HH 16
#define DD 64

typedef unsigned short u16;
typedef __attribute__((ext_vector_type(8))) short short8;
typedef __attribute__((ext_vector_type(4))) float f32x4;

__device__ __forceinline__ u16 f2bf(float x) {
    union { float f; unsigned u; } v; v.f = x;
    return (u16)((v.u + 0x7fffu + ((v.u >> 16) & 1u)) >> 16);
}

__device__ __forceinline__ float exp2_fast(float x) {
    float r;
    asm("v_exp_f32 %0, %1" : "=v"(r) : "v"(x));
    return r;
}

#define GLL16(gp, lp) \
    __builtin_amdgcn_global_load_lds( \
        (const __attribute__((address_space(1))) void*)(gp), \
        (__attribute__((address_space(3))) void*)(lp), 16, 0, 0)

#define BARRIER do { asm volatile("" ::: "memory"); \
                     __builtin_amdgcn_s_barrier();  \
                     asm volatile("" ::: "memory"); } while (0)
#define VMW4 asm volatile("s_waitcnt vmcnt(4)" ::: "memory")
#define VMW0 asm volatile("s_waitcnt vmcnt(0)" ::: "memory")
#define LG0  asm volatile("s_waitcnt lgkmcnt(0)" ::: "memory")
#define SCHED0 __builtin_amdgcn_sched_barrier(0)

// QSCALE = (1/sqrt(64)) * log2(e): softmax computed in base-2
#define QSCALE 0.18033688f

// ---------------------------------------------------------------------------
// fp32 -> bf16 conversion — weights only.
// ---------------------------------------------------------------------------
__global__ __launch_bounds__(256)
void cvt_bf16(const float* __restrict__ s0, const float* __restrict__ s1,
              const float* __restrict__ s2, const float* __restrict__ s3,
              u16* __restrict__ d0, u16* __restrict__ d1,
              u16* __restrict__ d2, u16* __restrict__ d3)
{
    const int z = blockIdx.y;
    const float* s; u16* d;
    switch (z) {
        case 0: s = s0; d = d0; break;
        case 1: s = s1; d = d1; break;
        case 2: s = s2; d = d2; break;
        default: s = s3; d = d3; break;
    }
    const int i = (blockIdx.x * 256 + threadIdx.x) * 8;   // n = 1048576
    float4 a = *(const float4*)(s + i);
    float4 b = *(const float4*)(s + i + 4);
    short8 r;
    r[0] = (short)f2bf(a.x); r[1] = (short)f2bf(a.y);
    r[2] = (short)f2bf(a.z); r[3] = (short)f2bf(a.w);
    r[4] = (short)f2bf(b.x); r[5] = (short)f2bf(b.y);
    r[6] = (short)f2bf(b.z); r[7] = (short)f2bf(b.w);
    *(short8*)(d + i) = r;
}

// ---------------------------------------------------------------------------
// Fused QKV GEMM — 128x64 tile (6 blocks/CU available; grid was the
// occupancy limiter at 3/CU with 128x128). Same 2-deep pipeline as R13:
// A fp32->regs (sets E/O) -> cvt -> LDS; B bf16 via gll (1 instr/stage);
// counted vmcnt(4) leaves A(k+2) in flight. Waves: 4 in M, per-wave 32x64,
// acc[2][4] (32 VGPR). N=64 => one head per block; epilogues simplified.
// Flat LDS (24 KB): LA[2][128][32] | LB[2][64][32]; V scratch 16 KB c LS.
// ---------------------------------------------------------------------------
__global__ __launch_bounds__(256, 4)
void gemm_qkv(const float* __restrict__ Xq, const float* __restrict__ Xk,
              const float* __restrict__ Xv,
              const u16* __restrict__ Wqb, const u16* __restrict__ Wkb,
              const u16* __restrict__ Wvb,
              const float* __restrict__ bq, const float* __restrict__ bk,
              const float* __restrict__ bv,
              u16* __restrict__ Qh, u16* __restrict__ Kh, u16* __restrict__ Vth)
{
    __shared__ __align__(16) u16 LS[12288];          // 24 KB
    typedef u16 rowA_t[128][32];
    typedef u16 rowB_t[64][32];
    rowA_t* LA = (rowA_t*)&LS[0];                    // LA[2][128][32] 16 KB
    rowB_t* LB = (rowB_t*)&LS[8192];                 // LB[2][64][32]   8 KB

    const int bid = blockIdx.x;
    const int swz = (bid & 7) * 192 + (bid >> 3);    // bijective, 1536 = 8*192
    const int z   = swz >> 9;                        // /512: 0=Q,1=K,2=V
    const int rem = swz & 511;
    const int m0  = (rem >> 4) * 128;
    const int n0  = (rem & 15) * 64;

    const float* X = (z == 0) ? Xq : (z == 1) ? Xk : Xv;
    const u16* Wt = (z == 0) ? Wqb : (z == 1) ? Wkb : Wvb;
    const float* bias = (z == 0) ? bq : (z == 1) ? bk : bv;
    u16* out = (z == 0) ? Qh : (z == 1) ? Kh : Vth;

    const int t = threadIdx.x;
    const int w = t >> 6, l = t & 63;
    const int ln = l & 15, hi = l >> 4;

    const int ar = t >> 1, ah = t & 1;
    const float* Xrow = X + (size_t)(m0 + ar) * 1024 + ah * 16;
    const int fa   = (ar >> 1) & 3;
    const int gpa0 = (2 * ah)     ^ fa;
    const int gpa1 = (2 * ah + 1) ^ fa;

    const int brow = t >> 2, gp4 = t & 3;            // 64 rows x 4 granules
    const int gl4  = gp4 ^ (brow & 3);
    const u16* Wp0 = Wt + (size_t)(n0 + brow) * 1024 + gl4 * 8;

    f32x4 acc[2][4];
    #pragma unroll
    for (int i = 0; i < 2; i++)
        #pragma unroll
        for (int j = 0; j < 4; j++)
            acc[i][j] = (f32x4){0.f, 0.f, 0.f, 0.f};

    float4 e0, e1, e2, e3;    // A set E (even tiles)
    float4 o0, o1, o2, o3;    // A set O (odd tiles)

#define ISSUE_B(buf, k0_) {                                                  \
        GLL16(Wp0 + (k0_), &LB[buf][brow][gp4 * 8]);                         \
    }
#define LOAD_A(S0, S1, S2, S3, k0_) {                                        \
        S0 = *(const float4*)(Xrow + (k0_));                                 \
        S1 = *(const float4*)(Xrow + (k0_) + 4);                             \
        S2 = *(const float4*)(Xrow + (k0_) + 8);                             \
        S3 = *(const float4*)(Xrow + (k0_) + 12);                            \
    }
#define CVT_A(buf, S0, S1, S2, S3) {                                         \
        uint4 u0, u1;                                                        \
        u0.x = f2bf(S0.x) | ((unsigned)f2bf(S0.y) << 16);                    \
        u0.y = f2bf(S0.z) | ((unsigned)f2bf(S0.w) << 16);                    \
        u0.z = f2bf(S1.x) | ((unsigned)f2bf(S1.y) << 16);                    \
        u0.w = f2bf(S1.z) | ((unsigned)f2bf(S1.w) << 16);                    \
        u1.x = f2bf(S2.x) | ((unsigned)f2bf(S2.y) << 16);                    \
        u1.y = f2bf(S2.z) | ((unsigned)f2bf(S2.w) << 16);                    \
        u1.z = f2bf(S3.x) | ((unsigned)f2bf(S3.y) << 16);                    \
        u1.w = f2bf(S3.z) | ((unsigned)f2bf(S3.w) << 16);                    \
        *(uint4*)&LA[buf][ar][gpa0 * 8] = u0;                                \
        *(uint4*)&LA[buf][ar][gpa1 * 8] = u1;                                \
    }
#define COMPUTE(la_, lb_) {                                                  \
        _Pragma("unroll")                                                    \
        for (int mi = 0; mi < 2; mi++)                                       \
            af[mi] = *(const short8*)&LA[la_][w*32 + mi*16 + ln]             \
                         [(hi ^ ((ln >> 1) & 3)) * 8];                       \
        _Pragma("unroll")                                                    \
        for (int nj = 0; nj < 4; nj++)                                       \
            bf[nj] = *(const short8*)&LB[lb_][nj*16 + ln]                    \
                         [(hi ^ (ln & 3)) * 8];                              \
        _Pragma("unroll")                                                    \
        for (int mi = 0; mi < 2; mi++)                                       \
            _Pragma("unroll")                                                \
            for (int nj = 0; nj < 4; nj++)                                   \
                acc[mi][nj] = __builtin_amdgcn_mfma_f32_16x16x32_bf16(       \
                    af[mi], bf[nj], acc[mi][nj], 0, 0, 0);                   \
    }

    short8 af[2], bf[4];

    // prologue: A(0)->E->LA0; B(0)->LB0; A(1)->O in flight
    LOAD_A(e0, e1, e2, e3, 0);
    CVT_A(0, e0, e1, e2, e3);
    ISSUE_B(0, 0); SCHED0;
    LOAD_A(o0, o1, o2, o3, 32); SCHED0;
    VMW4;                 // B(0) landed (leaves A(1): 4 loads)
    LG0; BARRIER;

    for (int it = 0; it < 15; ++it) {
        const int k0 = it * 64;
        // body E: tile 2it
        ISSUE_B(1, k0 + 32); SCHED0;
        LOAD_A(e0, e1, e2, e3, k0 + 64); SCHED0;
        COMPUTE(0, 0);
        CVT_A(1, o0, o1, o2, o3);
        VMW4;             // B(k+1) landed (leaves A(k+2): 4)
        LG0; BARRIER;
        // body O: tile 2it+1
        ISSUE_B(0, k0 + 64); SCHED0;
        LOAD_A(o0, o1, o2, o3, k0 + 96); SCHED0;
        COMPUTE(1, 1);
        CVT_A(0, e0, e1, e2, e3);
        VMW4;
        LG0; BARRIER;
    }
    // tail
    ISSUE_B(1, 992); SCHED0;
    COMPUTE(0, 0);
    CVT_A(1, o0, o1, o2, o3);
    VMW0;
    LG0; BARRIER;
    COMPUTE(1, 1);
#undef ISSUE_B
#undef LOAD_A
#undef CVT_A
#undef COMPUTE

    u16* T = &LS[0];                   // 16 KB scratch (in-bounds of 24 KB)
    const int b = m0 >> 11;
    const int h = n0 >> 6;             // single head per block

    if (z == 2) {
        // ---- V epilogue: T[64 nc][128 sr], coalesced stores ----
        #pragma unroll
        for (int mi = 0; mi < 2; mi++) {
            #pragma unroll
            for (int nj = 0; nj < 4; nj++) {
                const int nc = nj * 16 + ln;
                const float bv2 = bias[n0 + nc];
                const int sr0 = w * 32 + mi * 16 + hi * 4;
                uint2 pk;
                pk.x = f2bf(acc[mi][nj][0] + bv2)
                     | ((unsigned)f2bf(acc[mi][nj][1] + bv2) << 16);
                pk.y = f2bf(acc[mi][nj][2] + bv2)
                     | ((unsigned)f2bf(acc[mi][nj][3] + bv2) << 16);
                const int gp = (sr0 >> 2) ^ (nc & 31);
                *(uint2*)&T[nc * 128 + gp * 4] = pk;
            }
        }
        __syncthreads();
        const int s0 = m0 & 2047;
        const int sidx = t & 15;
        const int ncr0 = t >> 4;       // 0..15
        #pragma unroll
        for (int i = 0; i < 4; i++) {
            const int nc = ncr0 + i * 16;     // 0..63
            const int a  = sidx * 2;
            const int pa = a ^ (nc & 31);
            const int pb = (a + 1) ^ (nc & 31);
            uint2 lo  = *(const uint2*)&T[nc * 128 + pa * 4];
            uint2 hi2 = *(const uint2*)&T[nc * 128 + pb * 4];
            uint4 vd = make_uint4(lo.x, lo.y, hi2.x, hi2.y);
            *(uint4*)&out[(((size_t)(b * HH + h) * 64 + nc) << 11) + s0 + sidx * 8] = vd;
        }
    } else {
        // ---- Q/K epilogue: direct stores ----
        #pragma unroll
        for (int mi = 0; mi < 2; mi++) {
            #pragma unroll
            for (int nj = 0; nj < 4; nj++) {
                const int d = nj * 16 + ln;
                const float bv2 = bias[n0 + d];
                #pragma unroll
                for (int r = 0; r < 4; r++) {
                    const int m = m0 + w * 32 + mi * 16 + hi * 4 + r;
                    float v = acc[mi][nj][r] + bv2;
                    if (z == 0) v *= QSCALE;
                    const int s = m & 2047;
                    out[((((size_t)(b * HH + h)) << 11) + s) * 64 + d] = f2bf(v);
                }
            }
        }
    }
}

// ---------------------------------------------------------------------------
// Output projection GEMM (R13 version, unchanged).
// ---------------------------------------------------------------------------
__global__ __launch_bounds__(256)
void gemm_out(const u16* __restrict__ Xb, const u16* __restrict__ Wb,
              const float* __restrict__ bias, float* __restrict__ outp)
{
    __shared__ __align__(16) u16 As[2][64][32];
    __shared__ __align__(16) u16 Bs[2][128][32];

    const int bid = blockIdx.x;
    const int swz = (bid & 7) * 64 + (bid >> 3);
    const int m0  = (swz >> 3) * 64;
    const int n0  = (swz & 7) * 128;

    const int t = threadIdx.x;
    const int w = t >> 6, l = t & 63;
    const int ln = l & 15, hi = l >> 4;
    const int wr = w >> 1, wc = w & 1;

    const int row0 = t >> 2, gp4 = t & 3;
    const int gl4  = gp4 ^ (row0 & 3);

    f32x4 acc[2][4];
    #pragma unroll
    for (int i = 0; i < 2; i++)
        #pragma unroll
        for (int j = 0; j < 4; j++)
            acc[i][j] = (f32x4){0.f, 0.f, 0.f, 0.f};

#define OSTAGE(buf, k0_) { \
    GLL16(Xb + (size_t)(m0 + row0) * 1024 + (k0_) + gl4 * 8,        \
          &As[buf][row0][gp4 * 8]);                                  \
    GLL16(Wb + (size_t)(n0 + row0) * 1024 + (k0_) + gl4 * 8,        \
          &Bs[buf][row0][gp4 * 8]);                                  \
    GLL16(Wb + (size_t)(n0 + 64 + row0) * 1024 + (k0_) + gl4 * 8,   \
          &Bs[buf][row0 + 64][gp4 * 8]); }

    OSTAGE(0, 0);
    __syncthreads();
    int cur = 0;
    for (int k0 = 0; k0 < 1024; k0 += 32) {
        if (k0 + 32 < 1024) OSTAGE(cur ^ 1, k0 + 32);
        short8 af[2], bfr[4];
        #pragma unroll
        for (int mi = 0; mi < 2; mi++)
            af[mi] = *(const short8*)&As[cur][wr*32 + mi*16 + ln][(hi ^ (ln & 3))*8];
        #pragma unroll
        for (int nj = 0; nj < 4; nj++)
            bfr[nj] = *(const short8*)&Bs[cur][wc*64 + nj*16 + ln][(hi ^ (ln & 3))*8];
        #pragma unroll
        for (int mi = 0; mi < 2; mi++)
            #pragma unroll
            for (int nj = 0; nj < 4; nj++)
                acc[mi][nj] = __builtin_amdgcn_mfma_f32_16x16x32_bf16(
                    af[mi], bfr[nj], acc[mi][nj], 0, 0, 0);
        __syncthreads();
        cur ^= 1;
    }
#undef OSTAGE

    #pragma unroll
    for (int mi = 0; mi < 2; mi++) {
        #pragma unroll
        for (int nj = 0; nj < 4; nj++) {
            const int nb = n0 + wc * 64 + nj * 16 + ln;
            const float bv2 = bias[nb];
            #pragma unroll
            for (int r = 0; r < 4; r++) {
                const int m = m0 + wr * 32 + mi * 16 + hi * 4 + r;
                outp[(size_t)m * 1024 + nb] = acc[mi][nj][r] + bv2;
            }
        }
    }
}

// ---------------------------------------------------------------------------
// Flash attention, bf16 MFMA (R13: QBLK=64, setprio) — best known.
// ---------------------------------------------------------------------------
__global__ __launch_bounds__(256)
void attn_mfma(const u16* __restrict__ Qh, const u16* __restrict__ Kh,
               const u16* __restrict__ Vt, u16* __restrict__ Cc)
{
    __shared__ __align__(16) u16 Ks[2][2][4][64][8];
    __shared__ __align__(16) u16 Vs[2][2][4][64][8];
    __shared__ __align__(16) u16 Ps[4][16][64];
    const int bh = blockIdx.x;
    const int y  = 31 - blockIdx.y;
    const int q0 = y * 64;
    const int t = threadIdx.x, w = t >> 6, l = t & 63;
    const int ln = l & 15, hi = l >> 4;
    const size_t base = (size_t)bh * SS * DD;
    const int qg = q0 + w * 16 + ln;

    short8 qf0, qf1;
    {
        const u16* qp = Qh + base + (size_t)qg * 64 + hi * 8;
        qf0 = *(const short8*)qp;
        qf1 = *(const short8*)(qp + 32);
    }
    f32x4 o[4];
    #pragma unroll
    for (int dj = 0; dj < 4; dj++) o[dj] = (f32x4){0.f, 0.f, 0.f, 0.f};
    float mrun = -INFINITY, lrun = 0.f;

#define STAGE(buf, key0_)                                                        \
    {                                                                            \
        _Pragma("unroll")                                                        \
        for (int i_ = 0; i_ < 4; i_++) {                                         \
            const int id_ = w + i_ * 4;                                          \
            if (id_ < 8) {                                                       \
                const int dc_ = id_ >> 2, kg_ = id_ & 3;                         \
                const u16* gp_ = Kh + base + (size_t)((key0_) + l) * 64          \
                                 + dc_ * 32 + kg_ * 8;                           \
                GLL16(gp_, &Ks[buf][dc_][kg_][0][0]);                            \
            } else {                                                             \
                const int kc_ = (id_ >> 2) & 1, kg_ = id_ & 3;                   \
                const u16* gp_ = Vt + base + (size_t)l * SS + (key0_)            \
                                 + kc_ * 32 + kg_ * 8;                           \
                GLL16(gp_, &Vs[buf][kc_][kg_][0][0]);                            \
            }                                                                    \
        }                                                                        \
    }

    STAGE(0, 0);
    __syncthreads();
    int cur = 0;
    const int nkt = y + 1;
    for (int kt = 0; kt < nkt; kt++) {
        const int key0 = kt * 64;
        if (kt + 1 < nkt) STAGE(cur ^ 1, key0 + 64);

        f32x4 st[4];
        __builtin_amdgcn_s_setprio(1);
        #pragma unroll
        for (int kt4 = 0; kt4 < 4; kt4++) {
            short8 ka = *(const short8*)&Ks[cur][0][hi][kt4 * 16 + ln][0];
            short8 kb = *(const short8*)&Ks[cur][1][hi][kt4 * 16 + ln][0];
            f32x4 zz = (f32x4){0.f, 0.f, 0.f, 0.f};
            zz = __builtin_amdgcn_mfma_f32_16x16x32_bf16(ka, qf0, zz, 0, 0, 0);
            zz = __builtin_amdgcn_mfma_f32_16x16x32_bf16(kb, qf1, zz, 0, 0, 0);
            st[kt4] = zz;
        }
        __builtin_amdgcn_s_setprio(0);
        if (kt == y) {
            #pragma unroll
            for (int kt4 = 0; kt4 < 4; kt4++)
                #pragma unroll
                for (int r = 0; r < 4; r++)
                    if (key0 + kt4 * 16 + hi * 4 + r > qg)
                        st[kt4][r] = -INFINITY;
        }

        float tmax = -INFINITY;
        #pragma unroll
        for (int kt4 = 0; kt4 < 4; kt4++)
            #pragma unroll
            for (int r = 0; r < 4; r++)
                tmax = fmaxf(tmax, st[kt4][r]);
        tmax = fmaxf(tmax, __shfl_xor(tmax, 16));
        tmax = fmaxf(tmax, __shfl_xor(tmax, 32));
        if (__ballot(tmax > mrun + 8.f)) {
            const float mnew = fmaxf(mrun, tmax);
            const float alpha = exp2_fast(mrun - mnew);
            lrun *= alpha;
            mrun = mnew;
            #pragma unroll
            for (int r = 0; r < 4; r++) {
                const float ar = __shfl(alpha, hi * 4 + r);
                #pragma unroll
                for (int dj = 0; dj < 4; dj++) o[dj][r] *= ar;
            }
        }
        float p[4][4];
        float lsum = 0.f;
        #pragma unroll
        for (int kt4 = 0; kt4 < 4; kt4++)
            #pragma unroll
            for (int r = 0; r < 4; r++) {
                p[kt4][r] = exp2_fast(st[kt4][r] - mrun);
                lsum += p[kt4][r];
            }
        lsum += __shfl_xor(lsum, 16);
        lsum += __shfl_xor(lsum, 32);
        lrun += lsum;

        char* prow = ((char*)Ps) + (w * 16 + ln) * 128 + (hi & 1) * 8;
        #pragma unroll
        for (int kt4 = 0; kt4 < 4; kt4++) {
            unsigned dw0, dw1;
            asm("v_cvt_pk_bf16_f32 %0, %1, %2" : "=v"(dw0)
                : "v"(p[kt4][0]), "v"(p[kt4][1]));
            asm("v_cvt_pk_bf16_f32 %0, %1, %2" : "=v"(dw1)
                : "v"(p[kt4][2]), "v"(p[kt4][3]));
            const int g = (2 * kt4 + (hi >> 1)) ^ (ln & 7);
            *(uint2*)(prow + g * 16) = make_uint2(dw0, dw1);
        }

        __builtin_amdgcn_s_setprio(1);
        #pragma unroll
        for (int kc = 0; kc < 2; kc++) {
            const int gr = (kc * 4 + hi) ^ (ln & 7);
            short8 pa = *(const short8*)(((char*)Ps) + (w * 16 + ln) * 128 + gr * 16);
            #pragma unroll
            for (int dj = 0; dj < 4; dj++) {
                short8 vb = *(const short8*)&Vs[cur][kc][hi][dj * 16 + ln][0];
                o[dj] = __builtin_amdgcn_mfma_f32_16x16x32_bf16(pa, vb, o[dj], 0, 0, 0);
            }
        }
        __builtin_amdgcn_s_setprio(0);
        __syncthreads();
        cur ^= 1;
    }
#undef STAGE

    const float inv = 1.f / lrun;
    #pragma unroll
    for (int r = 0; r < 4; r++) {
        const float ir = __shfl(inv, hi * 4 + r);
        const int s = q0 + w * 16 + hi * 4 + r;
        const size_t ob = ((size_t)(bh >> 4) * SS + s) * EE + (bh & 15) * 64;
        #pragma unroll
        for (int dj = 0; dj < 4; dj++)
            Cc[ob + dj * 16 + ln] = f2bf(o[dj][r] * ir);
    }
}

extern "C" void kernel_launch(void* const* d_in, const int* in_sizes, int n_in,
                              void* d_out, int out_size, void* d_ws, size_t ws_size,
                              hipStream_t stream)
{
    (void)in_sizes; (void)n_in; (void)out_size; (void)ws_size;
    const float* query = (const float*)d_in[0];
    const float* key   = (const float*)d_in[1];
    const float* value = (const float*)d_in[2];
    const float* Wq = (const float*)d_in[4];
    const float* bq = (const float*)d_in[5];
    const float* Wk = (const float*)d_in[6];
    const float* bk = (const float*)d_in[7];
    const float* Wv = (const float*)d_in[8];
    const float* bv = (const float*)d_in[9];
    const float* Wo = (const float*)d_in[10];
    const float* bo = (const float*)d_in[11];
    float* out = (float*)d_out;

    char* ws = (char*)d_ws;
    u16* Wqb = (u16*)(ws + 25165824);
    u16* Wkb = (u16*)(ws + 27262976);
    u16* Wvb = (u16*)(ws + 29360128);
    u16* Wob = (u16*)(ws + 31457280);
    u16* Qh  = (u16*)(ws + 33554432);
    u16* Kh  = (u16*)(ws + 41943040);
    u16* Vth = (u16*)(ws + 50331648);
    u16* Cc  = (u16*)(ws + 58720256);

    cvt_bf16<<<dim3(512, 4), 256, 0, stream>>>(
        Wq, Wk, Wv, Wo, Wqb, Wkb, Wvb, Wob);

    gemm_qkv<<<1536, 256, 0, stream>>>(
        query, key, value, Wqb, Wkb, Wvb, bq, bk, bv, Qh, Kh, Vth);
    attn_mfma<<<dim3(32, 32), 256, 0, stream>>>(Qh, Kh, Vth, Cc);
    gemm_out<<<512, 256, 0, stream>>>(Cc, Wob, bo, out);
}

// Round 20
// 117.405 us; speedup vs baseline: 1.1904x; 1.1904x over previous
//
#include <hip/hip_runtime.h>
#include <math.h>

#define BB 2
#define SS 2048
#define EE 1024
#define HH 16
#define DD 64

typedef unsigned short u16;
typedef __attribute__((ext_vector_type(8))) short short8;
typedef __attribute__((ext_vector_type(4))) float f32x4;

__device__ __forceinline__ u16 f2bf(float x) {
    union { float f; unsigned u; } v; v.f = x;
    return (u16)((v.u + 0x7fffu + ((v.u >> 16) & 1u)) >> 16);
}

__device__ __forceinline__ float exp2_fast(float x) {
    float r;
    asm("v_exp_f32 %0, %1" : "=v"(r) : "v"(x));
    return r;
}

#define GLL16(gp, lp) \
    __builtin_amdgcn_global_load_lds( \
        (const __attribute__((address_space(1))) void*)(gp), \
        (__attribute__((address_space(3))) void*)(lp), 16, 0, 0)

#define BARRIER do { asm volatile("" ::: "memory"); \
                     __builtin_amdgcn_s_barrier();  \
                     asm volatile("" ::: "memory"); } while (0)
#define VMW4 asm volatile("s_waitcnt vmcnt(4)" ::: "memory")
#define VMW0 asm volatile("s_waitcnt vmcnt(0)" ::: "memory")
#define LG0  asm volatile("s_waitcnt lgkmcnt(0)" ::: "memory")
#define SCHED0 __builtin_amdgcn_sched_barrier(0)

// QSCALE = (1/sqrt(64)) * log2(e): softmax computed in base-2
#define QSCALE 0.18033688f

// ---------------------------------------------------------------------------
// fp32 -> bf16 conversion — weights only.
// ---------------------------------------------------------------------------
__global__ __launch_bounds__(256)
void cvt_bf16(const float* __restrict__ s0, const float* __restrict__ s1,
              const float* __restrict__ s2, const float* __restrict__ s3,
              u16* __restrict__ d0, u16* __restrict__ d1,
              u16* __restrict__ d2, u16* __restrict__ d3)
{
    const int z = blockIdx.y;
    const float* s; u16* d;
    switch (z) {
        case 0: s = s0; d = d0; break;
        case 1: s = s1; d = d1; break;
        case 2: s = s2; d = d2; break;
        default: s = s3; d = d3; break;
    }
    const int i = (blockIdx.x * 256 + threadIdx.x) * 8;   // n = 1048576
    float4 a = *(const float4*)(s + i);
    float4 b = *(const float4*)(s + i + 4);
    short8 r;
    r[0] = (short)f2bf(a.x); r[1] = (short)f2bf(a.y);
    r[2] = (short)f2bf(a.z); r[3] = (short)f2bf(a.w);
    r[4] = (short)f2bf(b.x); r[5] = (short)f2bf(b.y);
    r[6] = (short)f2bf(b.z); r[7] = (short)f2bf(b.w);
    *(short8*)(d + i) = r;
}

// ---------------------------------------------------------------------------
// Fused QKV GEMM (BEST-KNOWN = R13/R18): 128x128 tile, 2-deep A register
// pipeline (sets E/O) + counted-vmcnt barrier (vmcnt(4): waits only B(k+1);
// never drains in-flight A(k+2)). V epilogue: LDS transpose. Q/K: direct
// stores. Exhausted alternatives: depth-3 (spills), Q/K LDS epilogue
// (regressed), swapped-frag (neutral), 128x64 tile (regressed), 8-phase
// 256^2 (regressed), k-major staging (regressed).
// ---------------------------------------------------------------------------
__global__ __launch_bounds__(256, 3)
void gemm_qkv(const float* __restrict__ Xq, const float* __restrict__ Xk,
              const float* __restrict__ Xv,
              const u16* __restrict__ Wqb, const u16* __restrict__ Wkb,
              const u16* __restrict__ Wvb,
              const float* __restrict__ bq, const float* __restrict__ bk,
              const float* __restrict__ bv,
              u16* __restrict__ Qh, u16* __restrict__ Kh, u16* __restrict__ Vth)
{
    __shared__ __align__(16) u16 LS[2][2][128][32];   // LA=LS[0], LB=LS[1]
#define LA (LS[0])
#define LB (LS[1])

    const int bid = blockIdx.x;
    const int swz = (bid & 7) * 96 + (bid >> 3);
    const int z   = swz >> 8;
    const int rem = swz & 255;
    const int m0  = (rem >> 3) * 128;
    const int n0  = (rem & 7) * 128;

    const float* X = (z == 0) ? Xq : (z == 1) ? Xk : Xv;
    const u16* Wt = (z == 0) ? Wqb : (z == 1) ? Wkb : Wvb;
    const float* bias = (z == 0) ? bq : (z == 1) ? bk : bv;
    u16* out = (z == 0) ? Qh : (z == 1) ? Kh : Vth;

    const int t = threadIdx.x;
    const int w = t >> 6, l = t & 63;
    const int ln = l & 15, hi = l >> 4;
    const int wr = w >> 1, wc = w & 1;

    const int ar = t >> 1, ah = t & 1;
    const float* Xrow = X + (size_t)(m0 + ar) * 1024 + ah * 16;
    const int fa   = (ar >> 1) & 3;
    const int gpa0 = (2 * ah)     ^ fa;
    const int gpa1 = (2 * ah + 1) ^ fa;

    const int brow = t >> 2, gp4 = t & 3;
    const int gl4  = gp4 ^ (brow & 3);
    const u16* Wp0 = Wt + (size_t)(n0 + brow) * 1024 + gl4 * 8;
    const u16* Wp1 = Wt + (size_t)(n0 + 64 + brow) * 1024 + gl4 * 8;

    f32x4 acc[4][4];
    #pragma unroll
    for (int i = 0; i < 4; i++)
        #pragma unroll
        for (int j = 0; j < 4; j++)
            acc[i][j] = (f32x4){0.f, 0.f, 0.f, 0.f};

    float4 e0, e1, e2, e3;    // A register set E (even tiles)
    float4 o0, o1, o2, o3;    // A register set O (odd tiles)

#define ISSUE_B(buf, k0_) {                                                  \
        GLL16(Wp0 + (k0_), &LB[buf][brow][gp4 * 8]);                         \
        GLL16(Wp1 + (k0_), &LB[buf][brow + 64][gp4 * 8]);                    \
    }
#define LOAD_A(S0, S1, S2, S3, k0_) {                                        \
        S0 = *(const float4*)(Xrow + (k0_));                                 \
        S1 = *(const float4*)(Xrow + (k0_) + 4);                             \
        S2 = *(const float4*)(Xrow + (k0_) + 8);                             \
        S3 = *(const float4*)(Xrow + (k0_) + 12);                            \
    }
#define CVT_A(buf, S0, S1, S2, S3) {                                         \
        uint4 u0, u1;                                                        \
        u0.x = f2bf(S0.x) | ((unsigned)f2bf(S0.y) << 16);                    \
        u0.y = f2bf(S0.z) | ((unsigned)f2bf(S0.w) << 16);                    \
        u0.z = f2bf(S1.x) | ((unsigned)f2bf(S1.y) << 16);                    \
        u0.w = f2bf(S1.z) | ((unsigned)f2bf(S1.w) << 16);                    \
        u1.x = f2bf(S2.x) | ((unsigned)f2bf(S2.y) << 16);                    \
        u1.y = f2bf(S2.z) | ((unsigned)f2bf(S2.w) << 16);                    \
        u1.z = f2bf(S3.x) | ((unsigned)f2bf(S3.y) << 16);                    \
        u1.w = f2bf(S3.z) | ((unsigned)f2bf(S3.w) << 16);                    \
        *(uint4*)&LA[buf][ar][gpa0 * 8] = u0;                                \
        *(uint4*)&LA[buf][ar][gpa1 * 8] = u1;                                \
    }
#define COMPUTE(la_, lb_) {                                                  \
        _Pragma("unroll")                                                    \
        for (int mi = 0; mi < 4; mi++)                                       \
            af[mi] = *(const short8*)&LA[la_][wr*64 + mi*16 + ln]            \
                         [(hi ^ ((ln >> 1) & 3)) * 8];                       \
        _Pragma("unroll")                                                    \
        for (int nj = 0; nj < 4; nj++)                                       \
            bf[nj] = *(const short8*)&LB[lb_][wc*64 + nj*16 + ln]            \
                         [(hi ^ (ln & 3)) * 8];                              \
        _Pragma("unroll")                                                    \
        for (int mi = 0; mi < 4; mi++)                                       \
            _Pragma("unroll")                                                \
            for (int nj = 0; nj < 4; nj++)                                   \
                acc[mi][nj] = __builtin_amdgcn_mfma_f32_16x16x32_bf16(       \
                    af[mi], bf[nj], acc[mi][nj], 0, 0, 0);                   \
    }

    short8 af[4], bf[4];

    // prologue: A(0)->E -> LA0; B(0)->LB0; A(1)->O (stays in flight)
    LOAD_A(e0, e1, e2, e3, 0);
    CVT_A(0, e0, e1, e2, e3);
    ISSUE_B(0, 0); SCHED0;
    LOAD_A(o0, o1, o2, o3, 32); SCHED0;
    VMW4;                 // B(0) landed (leaves A(1) in flight)
    LG0; BARRIER;

    for (int it = 0; it < 15; ++it) {
        const int k0 = it * 64;
        // body E: tile k=2it
        ISSUE_B(1, k0 + 32); SCHED0;
        LOAD_A(e0, e1, e2, e3, k0 + 64); SCHED0;
        COMPUTE(0, 0);
        CVT_A(1, o0, o1, o2, o3);
        VMW4;             // B(k+1) landed (leaves A(k+2))
        LG0; BARRIER;
        // body O: tile k=2it+1
        ISSUE_B(0, k0 + 64); SCHED0;
        LOAD_A(o0, o1, o2, o3, k0 + 96); SCHED0;
        COMPUTE(1, 1);
        CVT_A(0, e0, e1, e2, e3);
        VMW4;             // B(k+1) landed (leaves A(k+2))
        LG0; BARRIER;
    }
    // tail: tile 30 (E): issue B(31)->LB1; consume A(31)=O -> LA1.
    ISSUE_B(1, 992); SCHED0;
    COMPUTE(0, 0);
    CVT_A(1, o0, o1, o2, o3);
    VMW0;                 // B(31) landed
    LG0; BARRIER;
    // tail: tile 31 (O)
    COMPUTE(1, 1);
#undef ISSUE_B
#undef LOAD_A
#undef CVT_A
#undef COMPUTE

    u16* T = &LS[0][0][0][0];          // 32 KB scratch, main loop done
    const int b = m0 >> 11;

    if (z == 2) {
        // ---- V epilogue (confirmed win): T[128 nc][128 sr] ----
        #pragma unroll
        for (int mi = 0; mi < 4; mi++) {
            #pragma unroll
            for (int nj = 0; nj < 4; nj++) {
                const int nc = wc * 64 + nj * 16 + ln;
                const float bv2 = bias[n0 + nc];
                const int sr0 = wr * 64 + mi * 16 + hi * 4;
                uint2 pk;
                pk.x = f2bf(acc[mi][nj][0] + bv2)
                     | ((unsigned)f2bf(acc[mi][nj][1] + bv2) << 16);
                pk.y = f2bf(acc[mi][nj][2] + bv2)
                     | ((unsigned)f2bf(acc[mi][nj][3] + bv2) << 16);
                const int gp = (sr0 >> 2) ^ (nc & 31);
                *(uint2*)&T[nc * 128 + gp * 4] = pk;
            }
        }
        __syncthreads();
        const int s0 = m0 & 2047;
        const int sidx = t & 15;
        const int ncr0 = t >> 4;
        #pragma unroll
        for (int i = 0; i < 8; i++) {
            const int nc = ncr0 + i * 16;
            const int a  = sidx * 2;
            const int pa = a ^ (nc & 31);
            const int pb = (a + 1) ^ (nc & 31);
            uint2 lo  = *(const uint2*)&T[nc * 128 + pa * 4];
            uint2 hi2 = *(const uint2*)&T[nc * 128 + pb * 4];
            uint4 vd = make_uint4(lo.x, lo.y, hi2.x, hi2.y);
            const int h = (n0 >> 6) + (nc >> 6);
            const int d = nc & 63;
            *(uint4*)&out[(((size_t)(b * HH + h) * 64 + d) << 11) + s0 + sidx * 8] = vd;
        }
    } else {
        // ---- Q/K epilogue: direct stores ----
        #pragma unroll
        for (int mi = 0; mi < 4; mi++) {
            #pragma unroll
            for (int nj = 0; nj < 4; nj++) {
                const int nb = n0 + wc * 64 + nj * 16 + ln;
                const float bv2 = bias[nb];
                const int h = nb >> 6, d = nb & 63;
                #pragma unroll
                for (int r = 0; r < 4; r++) {
                    const int m = m0 + wr * 64 + mi * 16 + hi * 4 + r;
                    float v = acc[mi][nj][r] + bv2;
                    if (z == 0) v *= QSCALE;
                    const int s = m & 2047;
                    out[((((size_t)(b * HH + h)) << 11) + s) * 64 + d] = f2bf(v);
                }
            }
        }
    }
#undef LA
#undef LB
}

// ---------------------------------------------------------------------------
// Output projection GEMM (R13 version).
// ---------------------------------------------------------------------------
__global__ __launch_bounds__(256)
void gemm_out(const u16* __restrict__ Xb, const u16* __restrict__ Wb,
              const float* __restrict__ bias, float* __restrict__ outp)
{
    __shared__ __align__(16) u16 As[2][64][32];
    __shared__ __align__(16) u16 Bs[2][128][32];

    const int bid = blockIdx.x;
    const int swz = (bid & 7) * 64 + (bid >> 3);
    const int m0  = (swz >> 3) * 64;
    const int n0  = (swz & 7) * 128;

    const int t = threadIdx.x;
    const int w = t >> 6, l = t & 63;
    const int ln = l & 15, hi = l >> 4;
    const int wr = w >> 1, wc = w & 1;

    const int row0 = t >> 2, gp4 = t & 3;
    const int gl4  = gp4 ^ (row0 & 3);

    f32x4 acc[2][4];
    #pragma unroll
    for (int i = 0; i < 2; i++)
        #pragma unroll
        for (int j = 0; j < 4; j++)
            acc[i][j] = (f32x4){0.f, 0.f, 0.f, 0.f};

#define OSTAGE(buf, k0_) { \
    GLL16(Xb + (size_t)(m0 + row0) * 1024 + (k0_) + gl4 * 8,        \
          &As[buf][row0][gp4 * 8]);                                  \
    GLL16(Wb + (size_t)(n0 + row0) * 1024 + (k0_) + gl4 * 8,        \
          &Bs[buf][row0][gp4 * 8]);                                  \
    GLL16(Wb + (size_t)(n0 + 64 + row0) * 1024 + (k0_) + gl4 * 8,   \
          &Bs[buf][row0 + 64][gp4 * 8]); }

    OSTAGE(0, 0);
    __syncthreads();
    int cur = 0;
    for (int k0 = 0; k0 < 1024; k0 += 32) {
        if (k0 + 32 < 1024) OSTAGE(cur ^ 1, k0 + 32);
        short8 af[2], bfr[4];
        #pragma unroll
        for (int mi = 0; mi < 2; mi++)
            af[mi] = *(const short8*)&As[cur][wr*32 + mi*16 + ln][(hi ^ (ln & 3))*8];
        #pragma unroll
        for (int nj = 0; nj < 4; nj++)
            bfr[nj] = *(const short8*)&Bs[cur][wc*64 + nj*16 + ln][(hi ^ (ln & 3))*8];
        #pragma unroll
        for (int mi = 0; mi < 2; mi++)
            #pragma unroll
            for (int nj = 0; nj < 4; nj++)
                acc[mi][nj] = __builtin_amdgcn_mfma_f32_16x16x32_bf16(
                    af[mi], bfr[nj], acc[mi][nj], 0, 0, 0);
        __syncthreads();
        cur ^= 1;
    }
#undef OSTAGE

    #pragma unroll
    for (int mi = 0; mi < 2; mi++) {
        #pragma unroll
        for (int nj = 0; nj < 4; nj++) {
            const int nb = n0 + wc * 64 + nj * 16 + ln;
            const float bv2 = bias[nb];
            #pragma unroll
            for (int r = 0; r < 4; r++) {
                const int m = m0 + wr * 32 + mi * 16 + hi * 4 + r;
                outp[(size_t)m * 1024 + nb] = acc[mi][nj][r] + bv2;
            }
        }
    }
}

// ---------------------------------------------------------------------------
// Flash attention, bf16 MFMA (R13: QBLK=64, setprio) — best known.
// ---------------------------------------------------------------------------
__global__ __launch_bounds__(256)
void attn_mfma(const u16* __restrict__ Qh, const u16* __restrict__ Kh,
               const u16* __restrict__ Vt, u16* __restrict__ Cc)
{
    __shared__ __align__(16) u16 Ks[2][2][4][64][8];
    __shared__ __align__(16) u16 Vs[2][2][4][64][8];
    __shared__ __align__(16) u16 Ps[4][16][64];
    const int bh = blockIdx.x;
    const int y  = 31 - blockIdx.y;
    const int q0 = y * 64;
    const int t = threadIdx.x, w = t >> 6, l = t & 63;
    const int ln = l & 15, hi = l >> 4;
    const size_t base = (size_t)bh * SS * DD;
    const int qg = q0 + w * 16 + ln;

    short8 qf0, qf1;
    {
        const u16* qp = Qh + base + (size_t)qg * 64 + hi * 8;
        qf0 = *(const short8*)qp;
        qf1 = *(const short8*)(qp + 32);
    }
    f32x4 o[4];
    #pragma unroll
    for (int dj = 0; dj < 4; dj++) o[dj] = (f32x4){0.f, 0.f, 0.f, 0.f};
    float mrun = -INFINITY, lrun = 0.f;

#define STAGE(buf, key0_)                                                        \
    {                                                                            \
        _Pragma("unroll")                                                        \
        for (int i_ = 0; i_ < 4; i_++) {                                         \
            const int id_ = w + i_ * 4;                                          \
            if (id_ < 8) {                                                       \
                const int dc_ = id_ >> 2, kg_ = id_ & 3;                         \
                const u16* gp_ = Kh + base + (size_t)((key0_) + l) * 64          \
                                 + dc_ * 32 + kg_ * 8;                           \
                GLL16(gp_, &Ks[buf][dc_][kg_][0][0]);                            \
            } else {                                                             \
                const int kc_ = (id_ >> 2) & 1, kg_ = id_ & 3;                   \
                const u16* gp_ = Vt + base + (size_t)l * SS + (key0_)            \
                                 + kc_ * 32 + kg_ * 8;                           \
                GLL16(gp_, &Vs[buf][kc_][kg_][0][0]);                            \
            }                                                                    \
        }                                                                        \
    }

    STAGE(0, 0);
    __syncthreads();
    int cur = 0;
    const int nkt = y + 1;
    for (int kt = 0; kt < nkt; kt++) {
        const int key0 = kt * 64;
        if (kt + 1 < nkt) STAGE(cur ^ 1, key0 + 64);

        f32x4 st[4];
        __builtin_amdgcn_s_setprio(1);
        #pragma unroll
        for (int kt4 = 0; kt4 < 4; kt4++) {
            short8 ka = *(const short8*)&Ks[cur][0][hi][kt4 * 16 + ln][0];
            short8 kb = *(const short8*)&Ks[cur][1][hi][kt4 * 16 + ln][0];
            f32x4 zz = (f32x4){0.f, 0.f, 0.f, 0.f};
            zz = __builtin_amdgcn_mfma_f32_16x16x32_bf16(ka, qf0, zz, 0, 0, 0);
            zz = __builtin_amdgcn_mfma_f32_16x16x32_bf16(kb, qf1, zz, 0, 0, 0);
            st[kt4] = zz;
        }
        __builtin_amdgcn_s_setprio(0);
        if (kt == y) {
            #pragma unroll
            for (int kt4 = 0; kt4 < 4; kt4++)
                #pragma unroll
                for (int r = 0; r < 4; r++)
                    if (key0 + kt4 * 16 + hi * 4 + r > qg)
                        st[kt4][r] = -INFINITY;
        }

        float tmax = -INFINITY;
        #pragma unroll
        for (int kt4 = 0; kt4 < 4; kt4++)
            #pragma unroll
            for (int r = 0; r < 4; r++)
                tmax = fmaxf(tmax, st[kt4][r]);
        tmax = fmaxf(tmax, __shfl_xor(tmax, 16));
        tmax = fmaxf(tmax, __shfl_xor(tmax, 32));
        if (__ballot(tmax > mrun + 8.f)) {
            const float mnew = fmaxf(mrun, tmax);
            const float alpha = exp2_fast(mrun - mnew);
            lrun *= alpha;
            mrun = mnew;
            #pragma unroll
            for (int r = 0; r < 4; r++) {
                const float ar = __shfl(alpha, hi * 4 + r);
                #pragma unroll
                for (int dj = 0; dj < 4; dj++) o[dj][r] *= ar;
            }
        }
        float p[4][4];
        float lsum = 0.f;
        #pragma unroll
        for (int kt4 = 0; kt4 < 4; kt4++)
            #pragma unroll
            for (int r = 0; r < 4; r++) {
                p[kt4][r] = exp2_fast(st[kt4][r] - mrun);
                lsum += p[kt4][r];
            }
        lsum += __shfl_xor(lsum, 16);
        lsum += __shfl_xor(lsum, 32);
        lrun += lsum;

        char* prow = ((char*)Ps) + (w * 16 + ln) * 128 + (hi & 1) * 8;
        #pragma unroll
        for (int kt4 = 0; kt4 < 4; kt4++) {
            unsigned dw0, dw1;
            asm("v_cvt_pk_bf16_f32 %0, %1, %2" : "=v"(dw0)
                : "v"(p[kt4][0]), "v"(p[kt4][1]));
            asm("v_cvt_pk_bf16_f32 %0, %1, %2" : "=v"(dw1)
                : "v"(p[kt4][2]), "v"(p[kt4][3]));
            const int g = (2 * kt4 + (hi >> 1)) ^ (ln & 7);
            *(uint2*)(prow + g * 16) = make_uint2(dw0, dw1);
        }

        __builtin_amdgcn_s_setprio(1);
        #pragma unroll
        for (int kc = 0; kc < 2; kc++) {
            const int gr = (kc * 4 + hi) ^ (ln & 7);
            short8 pa = *(const short8*)(((char*)Ps) + (w * 16 + ln) * 128 + gr * 16);
            #pragma unroll
            for (int dj = 0; dj < 4; dj++) {
                short8 vb = *(const short8*)&Vs[cur][kc][hi][dj * 16 + ln][0];
                o[dj] = __builtin_amdgcn_mfma_f32_16x16x32_bf16(pa, vb, o[dj], 0, 0, 0);
            }
        }
        __builtin_amdgcn_s_setprio(0);
        __syncthreads();
        cur ^= 1;
    }
#undef STAGE

    const float inv = 1.f / lrun;
    #pragma unroll
    for (int r = 0; r < 4; r++) {
        const float ir = __shfl(inv, hi * 4 + r);
        const int s = q0 + w * 16 + hi * 4 + r;
        const size_t ob = ((size_t)(bh >> 4) * SS + s) * EE + (bh & 15) * 64;
        #pragma unroll
        for (int dj = 0; dj < 4; dj++)
            Cc[ob + dj * 16 + ln] = f2bf(o[dj][r] * ir);
    }
}

extern "C" void kernel_launch(void* const* d_in, const int* in_sizes, int n_in,
                              void* d_out, int out_size, void* d_ws, size_t ws_size,
                              hipStream_t stream)
{
    (void)in_sizes; (void)n_in; (void)out_size; (void)ws_size;
    const float* query = (const float*)d_in[0];
    const float* key   = (const float*)d_in[1];
    const float* value = (const float*)d_in[2];
    const float* Wq = (const float*)d_in[4];
    const float* bq = (const float*)d_in[5];
    const float* Wk = (const float*)d_in[6];
    const float* bk = (const float*)d_in[7];
    const float* Wv = (const float*)d_in[8];
    const float* bv = (const float*)d_in[9];
    const float* Wo = (const float*)d_in[10];
    const float* bo = (const float*)d_in[11];
    float* out = (float*)d_out;

    char* ws = (char*)d_ws;
    u16* Wqb = (u16*)(ws + 25165824);
    u16* Wkb = (u16*)(ws + 27262976);
    u16* Wvb = (u16*)(ws + 29360128);
    u16* Wob = (u16*)(ws + 31457280);
    u16* Qh  = (u16*)(ws + 33554432);
    u16* Kh  = (u16*)(ws + 41943040);
    u16* Vth = (u16*)(ws + 50331648);
    u16* Cc  = (u16*)(ws + 58720256);

    cvt_bf16<<<dim3(512, 4), 256, 0, stream>>>(
        Wq, Wk, Wv, Wo, Wqb, Wkb, Wvb, Wob);

    gemm_qkv<<<768, 256, 0, stream>>>(
        query, key, value, Wqb, Wkb, Wvb, bq, bk, bv, Qh, Kh, Vth);
    attn_mfma<<<dim3(32, 32), 256, 0, stream>>>(Qh, Kh, Vth, Cc);
    gemm_out<<<512, 256, 0, stream>>>(Cc, Wob, bo, out);
}